// Round 4
// baseline (758.342 us; speedup 1.0000x reference)
//
#include <hip/hip_runtime.h>
#include <stdint.h>

// GNN layer on MI355X. Inputs f32, output f32 (per reference). Edge MLP via
// bf16 MFMA (f32 accum), attention with deferred normalization (f32 atomics),
// LN1, FFN(128->512->128) via MFMA, LN2.

typedef __attribute__((ext_vector_type(8))) short short8;   // 8 bf16 = 4 VGPRs
typedef __attribute__((ext_vector_type(4))) float floatx4;  // MFMA C/D

__device__ __forceinline__ float b2f(short s) {
    union { float f; uint32_t u; } v; v.u = ((uint32_t)(uint16_t)s) << 16; return v.f;
}
__device__ __forceinline__ short f2b(float f) {
    union { float f; uint32_t u; } v; v.f = f;
    uint32_t u = v.u;
    uint32_t r = (u + 0x7fff + ((u >> 16) & 1)) >> 16;  // RNE
    return (short)r;
}

#define NEG 0.01f

// ---------------- weight canonicalization f32 -> bf16, transposed ----------
// w1 [256][128] -> w1t [128][256]; w2,w3 [128][128] -> T; wi [128][512] ->
// wit [512][128]; wo [512][128] -> wot [128][512]
__global__ void prep_kernel(const float* __restrict__ w1, const float* __restrict__ w2,
                            const float* __restrict__ w3, const float* __restrict__ wi,
                            const float* __restrict__ wo,
                            short* __restrict__ w1t, short* __restrict__ w2t,
                            short* __restrict__ w3t, short* __restrict__ wit,
                            short* __restrict__ wot) {
    int t = blockIdx.x * 256 + threadIdx.x;  // 65536 threads
    if (t < 32768) { int k = t >> 7, n = t & 127; w1t[n * 256 + k] = f2b(w1[t]); }
    if (t < 16384) {
        int k = t >> 7, n = t & 127;
        w2t[n * 128 + k] = f2b(w2[t]);
        w3t[n * 128 + k] = f2b(w3[t]);
    }
    { int k = t >> 9, n = t & 511; wit[n * 128 + k] = f2b(wi[t]); }
    { int k = t >> 7, n = t & 127; wot[n * 512 + k] = f2b(wo[t]); }
}

// ---------------- edge kernel ----------------
// 64 edges/block, 256 threads (4 waves). Wave w owns output cols [32w,32w+32).
__global__ __launch_bounds__(256) void edge_kernel(
    const float* __restrict__ hV, const float* __restrict__ hE,
    const int* __restrict__ dst, int E,
    const short* __restrict__ w1t, const short* __restrict__ w2t,
    const short* __restrict__ w3t,
    const float* __restrict__ b1, const float* __restrict__ b2,
    const float* __restrict__ b3, const float* __restrict__ Av,
    float* __restrict__ num, float* __restrict__ denom) {
    __shared__ short smA[64 * 264];   // M (bf16, stride 264), later h2 (stride 136)
    __shared__ short smH1[64 * 136];
    __shared__ float s_att[64];
    __shared__ int s_dst[64];
    __shared__ float s_part[64][4];

    const int tid = threadIdx.x;
    const int lane = tid & 63;
    const int wv = tid >> 6;
    const int e0 = blockIdx.x * 64;

    if (tid < 64) {
        int e = e0 + tid; if (e >= E) e = E - 1;
        s_dst[tid] = dst[e];
    }
    __syncthreads();

    // stage M = [h_V[dst] | h_E] (64 rows x 256), f32 -> bf16
#pragma unroll
    for (int i = 0; i < 8; ++i) {
        int c = tid + i * 256;
        int row = c >> 5;
        int off = (c & 31) * 8;
        int e = e0 + row; if (e >= E) e = E - 1;
        const float* src = (off < 128)
            ? (hV + (size_t)s_dst[row] * 128 + off)
            : (hE + (size_t)e * 128 + (off - 128));
        float4 a0 = *(const float4*)(src);
        float4 a1 = *(const float4*)(src + 4);
        short8 v;
        v[0] = f2b(a0.x); v[1] = f2b(a0.y); v[2] = f2b(a0.z); v[3] = f2b(a0.w);
        v[4] = f2b(a1.x); v[5] = f2b(a1.y); v[6] = f2b(a1.z); v[7] = f2b(a1.w);
        *(short8*)(&smA[row * 264 + off]) = v;
    }
    __syncthreads();

    // attention: att = exp(sigmoid(lrelu(m . A)))  (A read in f32)
    {
        int e = tid >> 2, p = tid & 3;
        const short* mr = &smA[e * 264 + p * 64];
        const float* ar = &Av[p * 64];
        float s = 0.f;
#pragma unroll 8
        for (int k = 0; k < 64; ++k) s += b2f(mr[k]) * ar[k];
        s_part[e][p] = s;
    }
    __syncthreads();
    if (tid < 64) {
        float x = s_part[tid][0] + s_part[tid][1] + s_part[tid][2] + s_part[tid][3];
        float z = (x >= 0.f) ? x : NEG * x;
        float a = expf(1.f / (1.f + expf(-z)));
        s_att[tid] = a;
        if (e0 + tid < E) unsafeAtomicAdd(&denom[s_dst[tid]], a);
    }
    __syncthreads();

    const int q = lane >> 4, r = lane & 15;
    const int cb = wv * 32;
    floatx4 zero = {0.f, 0.f, 0.f, 0.f};

    // ---- layer 1: h1 = lrelu(M @ w1 + b1), K=256 ----
    {
        floatx4 acc[4][2];
#pragma unroll
        for (int rt = 0; rt < 4; ++rt) { acc[rt][0] = zero; acc[rt][1] = zero; }
#pragma unroll
        for (int ks = 0; ks < 8; ++ks) {
            short8 bA = *(const short8*)(w1t + (cb + r) * 256 + ks * 32 + q * 8);
            short8 bB = *(const short8*)(w1t + (cb + 16 + r) * 256 + ks * 32 + q * 8);
#pragma unroll
            for (int rt = 0; rt < 4; ++rt) {
                short8 a = *(const short8*)(&smA[(rt * 16 + r) * 264 + ks * 32 + q * 8]);
                acc[rt][0] = __builtin_amdgcn_mfma_f32_16x16x32_bf16(a, bA, acc[rt][0], 0, 0, 0);
                acc[rt][1] = __builtin_amdgcn_mfma_f32_16x16x32_bf16(a, bB, acc[rt][1], 0, 0, 0);
            }
        }
#pragma unroll
        for (int ct = 0; ct < 2; ++ct) {
            int col = cb + ct * 16 + r;
            float bias = b1[col];
#pragma unroll
            for (int rt = 0; rt < 4; ++rt)
#pragma unroll
                for (int rr = 0; rr < 4; ++rr) {
                    int row = rt * 16 + q * 4 + rr;
                    float v = acc[rt][ct][rr] + bias;
                    v = (v >= 0.f) ? v : NEG * v;
                    smH1[row * 136 + col] = f2b(v);
                }
        }
    }
    __syncthreads();

    // ---- layer 2: h2 = lrelu(h1 @ w2 + b2), K=128; h2 -> smA region ----
    {
        floatx4 acc[4][2];
#pragma unroll
        for (int rt = 0; rt < 4; ++rt) { acc[rt][0] = zero; acc[rt][1] = zero; }
#pragma unroll
        for (int ks = 0; ks < 4; ++ks) {
            short8 bA = *(const short8*)(w2t + (cb + r) * 128 + ks * 32 + q * 8);
            short8 bB = *(const short8*)(w2t + (cb + 16 + r) * 128 + ks * 32 + q * 8);
#pragma unroll
            for (int rt = 0; rt < 4; ++rt) {
                short8 a = *(const short8*)(&smH1[(rt * 16 + r) * 136 + ks * 32 + q * 8]);
                acc[rt][0] = __builtin_amdgcn_mfma_f32_16x16x32_bf16(a, bA, acc[rt][0], 0, 0, 0);
                acc[rt][1] = __builtin_amdgcn_mfma_f32_16x16x32_bf16(a, bB, acc[rt][1], 0, 0, 0);
            }
        }
        short* smH2 = smA;  // M fully consumed
#pragma unroll
        for (int ct = 0; ct < 2; ++ct) {
            int col = cb + ct * 16 + r;
            float bias = b2[col];
#pragma unroll
            for (int rt = 0; rt < 4; ++rt)
#pragma unroll
                for (int rr = 0; rr < 4; ++rr) {
                    int row = rt * 16 + q * 4 + rr;
                    float v = acc[rt][ct][rr] + bias;
                    v = (v >= 0.f) ? v : NEG * v;
                    smH2[row * 136 + col] = f2b(v);
                }
        }
    }
    __syncthreads();

    // ---- layer 3: hm = h2 @ w3 + b3; scatter num += att*hm ----
    {
        const short* smH2 = smA;
        floatx4 acc[4][2];
#pragma unroll
        for (int rt = 0; rt < 4; ++rt) { acc[rt][0] = zero; acc[rt][1] = zero; }
#pragma unroll
        for (int ks = 0; ks < 4; ++ks) {
            short8 bA = *(const short8*)(w3t + (cb + r) * 128 + ks * 32 + q * 8);
            short8 bB = *(const short8*)(w3t + (cb + 16 + r) * 128 + ks * 32 + q * 8);
#pragma unroll
            for (int rt = 0; rt < 4; ++rt) {
                short8 a = *(const short8*)(&smH2[(rt * 16 + r) * 136 + ks * 32 + q * 8]);
                acc[rt][0] = __builtin_amdgcn_mfma_f32_16x16x32_bf16(a, bA, acc[rt][0], 0, 0, 0);
                acc[rt][1] = __builtin_amdgcn_mfma_f32_16x16x32_bf16(a, bB, acc[rt][1], 0, 0, 0);
            }
        }
#pragma unroll
        for (int ct = 0; ct < 2; ++ct) {
            int col = cb + ct * 16 + r;
            float bias = b3[col];
#pragma unroll
            for (int rt = 0; rt < 4; ++rt)
#pragma unroll
                for (int rr = 0; rr < 4; ++rr) {
                    int row = rt * 16 + q * 4 + rr;
                    if (e0 + row < E) {
                        float v = (acc[rt][ct][rr] + bias) * s_att[row];
                        unsafeAtomicAdd(&num[(size_t)s_dst[row] * 128 + col], v);
                    }
                }
        }
    }
}

// ---------------- node LN1 -> bf16 ----------------
__global__ __launch_bounds__(256) void node1_kernel(
    const float* __restrict__ hV, const float* __restrict__ num,
    const float* __restrict__ denom, const float* __restrict__ g1,
    const float* __restrict__ be1, int N, short* __restrict__ hv1b) {
    int n = blockIdx.x * 4 + (threadIdx.x >> 6);
    int lane = threadIdx.x & 63;
    if (n >= N) return;
    float d = denom[n];
    float inv = (d > 0.f) ? 1.f / (d * 30.f) : 0.f;
    size_t base = (size_t)n * 128;
    float x0 = hV[base + lane] + num[base + lane] * inv;
    float x1 = hV[base + lane + 64] + num[base + lane + 64] * inv;
    float s = x0 + x1, sq = x0 * x0 + x1 * x1;
#pragma unroll
    for (int o = 32; o > 0; o >>= 1) {
        s += __shfl_down(s, o);
        sq += __shfl_down(sq, o);
    }
    s = __shfl(s, 0); sq = __shfl(sq, 0);
    float mu = s * 0.0078125f;
    float var = sq * 0.0078125f - mu * mu;
    float rstd = rsqrtf(var + 1e-6f);
    float y0 = g1[lane] * (x0 - mu) * rstd + be1[lane];
    float y1 = g1[lane + 64] * (x1 - mu) * rstd + be1[lane + 64];
    hv1b[base + lane] = f2b(y0);
    hv1b[base + lane + 64] = f2b(y1);
}

// ---------------- FFN + LN2 (f32 output) ----------------
// 32 nodes/block. layer-in: wave w -> cols [128w,128w+128); layer-out: [32w,32w+32).
__global__ __launch_bounds__(256) void ffn_kernel(
    const short* __restrict__ hv1b,
    const short* __restrict__ wit, const short* __restrict__ wot,
    const float* __restrict__ bi, const float* __restrict__ bo,
    const float* __restrict__ g2, const float* __restrict__ be2,
    int N, float* __restrict__ out) {
    __shared__ short smX[32 * 136];
    __shared__ short smT[32 * 520];
    __shared__ float smD[32][128];
    __shared__ float smR[32][8][2];
    __shared__ float smS[32][2];

    const int tid = threadIdx.x;
    const int lane = tid & 63;
    const int wv = tid >> 6;
    const int nb = blockIdx.x * 32;

#pragma unroll
    for (int i = 0; i < 2; ++i) {
        int c = tid + i * 256;
        int row = c >> 4;
        int off = (c & 15) * 8;
        int n = nb + row; if (n >= N) n = N - 1;
        *(int4*)(&smX[row * 136 + off]) = *(const int4*)(hv1b + (size_t)n * 128 + off);
    }
    __syncthreads();

    const int q = lane >> 4, r = lane & 15;
    floatx4 zero = {0.f, 0.f, 0.f, 0.f};

    {   // T = relu(X @ wi + bi), K=128
        floatx4 acc[2][8];
#pragma unroll
        for (int ct = 0; ct < 8; ++ct) { acc[0][ct] = zero; acc[1][ct] = zero; }
        const int cb = wv * 128;
#pragma unroll
        for (int ks = 0; ks < 4; ++ks) {
            short8 a0 = *(const short8*)(&smX[r * 136 + ks * 32 + q * 8]);
            short8 a1 = *(const short8*)(&smX[(16 + r) * 136 + ks * 32 + q * 8]);
#pragma unroll
            for (int ct = 0; ct < 8; ++ct) {
                short8 b = *(const short8*)(wit + (size_t)(cb + ct * 16 + r) * 128 + ks * 32 + q * 8);
                acc[0][ct] = __builtin_amdgcn_mfma_f32_16x16x32_bf16(a0, b, acc[0][ct], 0, 0, 0);
                acc[1][ct] = __builtin_amdgcn_mfma_f32_16x16x32_bf16(a1, b, acc[1][ct], 0, 0, 0);
            }
        }
#pragma unroll
        for (int ct = 0; ct < 8; ++ct) {
            int col = cb + ct * 16 + r;
            float bias = bi[col];
#pragma unroll
            for (int rt = 0; rt < 2; ++rt)
#pragma unroll
                for (int rr = 0; rr < 4; ++rr) {
                    int row = rt * 16 + q * 4 + rr;
                    float v = acc[rt][ct][rr] + bias;
                    smT[row * 520 + col] = f2b(v > 0.f ? v : 0.f);
                }
        }
    }
    __syncthreads();

    {   // dh2 = T @ wo + bo, K=512
        floatx4 acc[2][2];
        acc[0][0] = zero; acc[0][1] = zero; acc[1][0] = zero; acc[1][1] = zero;
        const int cb = wv * 32;
#pragma unroll
        for (int ks = 0; ks < 16; ++ks) {
            short8 bA = *(const short8*)(wot + (size_t)(cb + r) * 512 + ks * 32 + q * 8);
            short8 bB = *(const short8*)(wot + (size_t)(cb + 16 + r) * 512 + ks * 32 + q * 8);
            short8 a0 = *(const short8*)(&smT[r * 520 + ks * 32 + q * 8]);
            short8 a1 = *(const short8*)(&smT[(16 + r) * 520 + ks * 32 + q * 8]);
            acc[0][0] = __builtin_amdgcn_mfma_f32_16x16x32_bf16(a0, bA, acc[0][0], 0, 0, 0);
            acc[0][1] = __builtin_amdgcn_mfma_f32_16x16x32_bf16(a0, bB, acc[0][1], 0, 0, 0);
            acc[1][0] = __builtin_amdgcn_mfma_f32_16x16x32_bf16(a1, bA, acc[1][0], 0, 0, 0);
            acc[1][1] = __builtin_amdgcn_mfma_f32_16x16x32_bf16(a1, bB, acc[1][1], 0, 0, 0);
        }
#pragma unroll
        for (int ct = 0; ct < 2; ++ct) {
            int col = cb + ct * 16 + r;
            float bias = bo[col];
#pragma unroll
            for (int rt = 0; rt < 2; ++rt)
#pragma unroll
                for (int rr = 0; rr < 4; ++rr) {
                    int row = rt * 16 + q * 4 + rr;
                    smD[row][col] = acc[rt][ct][rr] + bias;
                }
        }
    }
    __syncthreads();

    {   // LN2 over x = hv1 + dh2
        int row = tid >> 3, j = tid & 7;
        int n = nb + row;
        float s = 0.f, sq = 0.f;
#pragma unroll
        for (int c = j * 16; c < j * 16 + 16; ++c) {
            float x = (n < N ? b2f(hv1b[(size_t)n * 128 + c]) : 0.f) + smD[row][c];
            smD[row][c] = x;
            s += x; sq += x * x;
        }
        smR[row][j][0] = s; smR[row][j][1] = sq;
    }
    __syncthreads();
    if ((tid & 7) == 0) {
        int row = tid >> 3;
        float s = 0.f, sq = 0.f;
#pragma unroll
        for (int j = 0; j < 8; ++j) { s += smR[row][j][0]; sq += smR[row][j][1]; }
        float mu = s * 0.0078125f;
        float var = sq * 0.0078125f - mu * mu;
        smS[row][0] = mu;
        smS[row][1] = rsqrtf(var + 1e-6f);
    }
    __syncthreads();
    {
        int row = tid >> 3, j = tid & 7;
        int n = nb + row;
        if (n < N) {
            float mu = smS[row][0], rstd = smS[row][1];
#pragma unroll
            for (int c = j * 16; c < j * 16 + 16; ++c) {
                float y = g2[c] * (smD[row][c] - mu) * rstd + be2[c];
                out[(size_t)n * 128 + c] = y;   // f32 output
            }
        }
    }
}

extern "C" void kernel_launch(void* const* d_in, const int* in_sizes, int n_in,
                              void* d_out, int out_size, void* d_ws, size_t ws_size,
                              hipStream_t stream) {
    const float* hV  = (const float*)d_in[0];
    const float* hE  = (const float*)d_in[1];
    const float* w1  = (const float*)d_in[2];
    const float* b1  = (const float*)d_in[3];
    const float* w2  = (const float*)d_in[4];
    const float* b2  = (const float*)d_in[5];
    const float* w3  = (const float*)d_in[6];
    const float* b3  = (const float*)d_in[7];
    const float* Av  = (const float*)d_in[8];
    const float* wi  = (const float*)d_in[9];
    const float* bi  = (const float*)d_in[10];
    const float* wo  = (const float*)d_in[11];
    const float* bo  = (const float*)d_in[12];
    const float* g1  = (const float*)d_in[13];
    const float* be1 = (const float*)d_in[14];
    const float* g2  = (const float*)d_in[15];
    const float* be2 = (const float*)d_in[16];
    const int* eidx  = (const int*)d_in[17];

    const int N = in_sizes[0] / 128;
    const int E = in_sizes[1] / 128;

    char* ws = (char*)d_ws;
    size_t o_num  = 0;                                             // N*128 f32
    size_t o_den  = o_num + (size_t)N * 128 * 4;                   // N f32
    size_t o_hv1b = (o_den + (size_t)N * 4 + 255) & ~(size_t)255;  // N*128 bf16
    size_t o_w1t  = o_hv1b + (size_t)N * 128 * 2;
    size_t o_w2t  = o_w1t + 128 * 256 * 2;
    size_t o_w3t  = o_w2t + 128 * 128 * 2;
    size_t o_wit  = o_w3t + 128 * 128 * 2;
    size_t o_wot  = o_wit + 512 * 128 * 2;

    float* num   = (float*)(ws + o_num);
    float* den   = (float*)(ws + o_den);
    short* hv1b  = (short*)(ws + o_hv1b);
    short* w1t   = (short*)(ws + o_w1t);
    short* w2t   = (short*)(ws + o_w2t);
    short* w3t   = (short*)(ws + o_w3t);
    short* wit   = (short*)(ws + o_wit);
    short* wot   = (short*)(ws + o_wot);

    hipMemsetAsync(ws, 0, o_den + (size_t)N * 4, stream);
    prep_kernel<<<256, 256, 0, stream>>>(w1, w2, w3, wi, wo, w1t, w2t, w3t, wit, wot);
    edge_kernel<<<(E + 63) / 64, 256, 0, stream>>>(hV, hE, eidx, E, w1t, w2t, w3t,
                                                   b1, b2, b3, Av, num, den);
    node1_kernel<<<(N + 3) / 4, 256, 0, stream>>>(hV, num, den, g1, be1, N, hv1b);
    ffn_kernel<<<(N + 31) / 32, 256, 0, stream>>>(hv1b, wit, wot, bi, bo, g2, be2,
                                                  N, (float*)d_out);
}